// Round 2
// baseline (2051.133 us; speedup 1.0000x reference)
//
#include <hip/hip_runtime.h>

#define BB   256
#define TT   512
#define FF   8
#define HH   256
#define LL   4
#define OO   8
#define BETA 0.8f
#define THRV 1.0f

// d_out layout (floats): outputs | hidden | prev_obs | readout
#define OFF_OUT  0
#define OFF_HID  (BB*TT*OO)
#define OFF_PREV (OFF_HID + (size_t)BB*TT*LL*HH)
#define OFF_RO   (OFF_PREV + BB*TT*FF)

typedef float nf4 __attribute__((ext_vector_type(4)));

__device__ __forceinline__ float tree32_masked(const float* W, int base, int n) {
    float t[32];
    #pragma unroll
    for (int q = 0; q < 32; ++q) t[q] = (base + q < n) ? W[q] : 0.f;
    #pragma unroll
    for (int s = 16; s > 0; s >>= 1)
        #pragma unroll
        for (int q = 0; q < s; ++q) t[q] += t[q + s];
    return t[0];
}

__device__ __forceinline__ float tree32(const float* W) {
    float t[32];
    #pragma unroll
    for (int q = 0; q < 32; ++q) t[q] = W[q];
    #pragma unroll
    for (int s = 16; s > 0; s >>= 1)
        #pragma unroll
        for (int q = 0; q < s; ++q) t[q] += t[q + s];
    return t[0];
}

// Deep-pipelined sparse row-sum over LDS list of pre-scaled row offsets (h<<8).
// Chunk-0 list reads are issued UNCONDITIONALLY so they overlap the LDS read
// of n (trip count resolves exactly when addresses become available -> zero
// added latency). 32 speculative global loads per chunk; stale list entries
// are always valid in-bounds row offsets for this layer's matrix, masked at
// accumulate. 2-deep chunk pipeline + log-depth tree reduction.
__device__ __forceinline__ float scan_chunks(const int* lst, int n, const float* __restrict__ Wb)
{
    int4 La[8];
    #pragma unroll
    for (int q = 0; q < 8; ++q) La[q] = ((const int4*)lst)[q];
    if (n <= 0) return 0.f;
    float Wa[32];
    #pragma unroll
    for (int q = 0; q < 8; ++q) {
        Wa[4*q+0] = Wb[La[q].x]; Wa[4*q+1] = Wb[La[q].y];
        Wa[4*q+2] = Wb[La[q].z]; Wa[4*q+3] = Wb[La[q].w];
    }
    if (n <= 32) return tree32_masked(Wa, 0, n);

    float acc = 0.f;
    int base = 0;
    const int nch = (n + 31) >> 5;
    #pragma unroll 1
    for (int c = 1; c < nch; ++c) {
        int4 Lb[8];
        #pragma unroll
        for (int q = 0; q < 8; ++q) Lb[q] = ((const int4*)(lst + 32 * c))[q];
        float Wn[32];
        #pragma unroll
        for (int q = 0; q < 8; ++q) {
            Wn[4*q+0] = Wb[Lb[q].x]; Wn[4*q+1] = Wb[Lb[q].y];
            Wn[4*q+2] = Wb[Lb[q].z]; Wn[4*q+3] = Wb[Lb[q].w];
        }
        acc += tree32(Wa);           // chunk c-1 is full (32c <= n for c < nch)
        #pragma unroll
        for (int q = 0; q < 32; ++q) Wa[q] = Wn[q];
        base += 32;
    }
    return acc + tree32_masked(Wa, base, n);
}

// LIF update + spike publish: ballot -> LDS atomicAdd gives this wave a
// contiguous base (segment order irrelevant for a sum) -> list write.
// All pre-barrier: one barrier per layer.
#define UPDATE_PUBLISH(mreg, li, cval, rowptr)                                  \
    {                                                                           \
        float reset_ = ((mreg) > THRV) ? THRV : 0.f;                            \
        (mreg) = BETA * (mreg) + (cval) - reset_;                               \
        int spk_ = ((mreg) > THRV) ? 1 : 0;                                     \
        __builtin_nontemporal_store((mreg), (rowptr) + h);                      \
        unsigned long long bm_ = __ballot(spk_);                                \
        int base_ = 0;                                                          \
        if (lane == 0) base_ = atomicAdd(&s_total[li], __popcll(bm_));          \
        base_ = __shfl(base_, 0);                                               \
        if (spk_)                                                               \
            s_list[li][base_ + __popcll(bm_ & ((1ull << lane) - 1ull))] = h << 8;\
    }

__launch_bounds__(320, 1)
__global__ void snn_kernel(const float* __restrict__ x,
                           const float* __restrict__ hidden_in,
                           const float* __restrict__ readout_in,
                           const float* __restrict__ W1,
                           const float* __restrict__ b1,
                           const float* __restrict__ Wh,
                           const float* __restrict__ bh,
                           const float* __restrict__ Wout,
                           const float* __restrict__ bout,
                           float* __restrict__ out)
{
    // lists pre-zeroed; stale entries are valid in-bounds row offsets, so
    // speculative chunk loads never fault and get masked at accumulate.
    __shared__ __align__(16) int s_list[3][256];
    __shared__ int                s_total[3];
    __shared__ unsigned long long s_mask3[4];

    const int tid  = threadIdx.x;
    const int b    = blockIdx.x;
    const int lane = tid & 63;
    const int wave = tid >> 6;          // 0..3: h-owners, 4: readout wave
    const int h    = tid & (HH - 1);

    for (int i = tid; i < 3 * 256; i += 320) ((int*)s_list)[i] = 0;
    if (tid < 3) s_total[tid] = 0;
    if (tid < 4) s_mask3[tid] = 0ull;

    // prev_obs = x (pure copy), nontemporal
    {
        const nf4* xs = (const nf4*)(x + (size_t)b * TT * FF);
        nf4*       po = (nf4*)(out + OFF_PREV + (size_t)b * TT * FF);
        for (int i = tid; i < (TT * FF) / 4; i += 320)
            __builtin_nontemporal_store(xs[i], po + i);
    }

    float m0 = 0, m1 = 0, m2 = 0, m3 = 0;
    float w1c[FF];
    float b1c = 0, bhc0 = 0, bhc1 = 0, bhc2 = 0;
    if (tid < 256) {
        const size_t hb = (size_t)b * TT * LL * HH;
        m0 = hidden_in[hb + 0 * HH + h];
        m1 = hidden_in[hb + 1 * HH + h];
        m2 = hidden_in[hb + 2 * HH + h];
        m3 = hidden_in[hb + 3 * HH + h];
        #pragma unroll
        for (int f = 0; f < FF; ++f) w1c[f] = W1[f * HH + h];
        b1c  = b1[h];
        bhc0 = bh[0 * HH + h]; bhc1 = bh[1 * HH + h]; bhc2 = bh[2 * HH + h];
    }

    // wave 4: lane = (o, seg) pair; ro recurrence lives in lanes 0..7
    const int o8  = lane & 7;
    const int seg = lane >> 3;
    float ro = 0.f, boutc = 0.f;
    if (wave == 4 && lane < 8) {
        ro    = readout_in[(size_t)b * TT * OO + lane];
        boutc = bout[lane];
    }

    const float* xb  = x + (size_t)b * TT * FF;
    const float* Wb0 = Wh + h;
    const float* Wb1 = Wh + 1 * HH * HH + h;
    const float* Wb2 = Wh + 2 * HH * HH + h;
    float* hid_out = out + OFF_HID + (size_t)b * TT * LL * HH;
    float* out_o   = out + OFF_OUT + (size_t)b * TT * OO;
    float* out_r   = out + OFF_RO  + (size_t)b * TT * OO;

    nf4 xv0 = {0, 0, 0, 0}, xv1 = {0, 0, 0, 0};

    __syncthreads();    // init (zeroed lists/totals) visible before prologue

    // ---- prologue: layer-0 for t=0 ----
    if (tid < 256) {
        xv0 = ((const nf4*)xb)[0];
        xv1 = ((const nf4*)xb)[1];
        float c = b1c + xv0.x * w1c[0] + xv0.y * w1c[1] + xv0.z * w1c[2] + xv0.w * w1c[3]
                      + xv1.x * w1c[4] + xv1.y * w1c[5] + xv1.z * w1c[6] + xv1.w * w1c[7];
        UPDATE_PUBLISH(m0, 0, c, hid_out + 0);
    }
    __syncthreads();

    #pragma unroll 1
    for (int t = 0; t < TT; ++t) {
        float* hrow = hid_out + (size_t)t * LL * HH;

        // ---- P_A: scan list0 -> layer-1; x prefetch for t+1;
        //           wave4 overlaps readout of t-1 here ----
        if (tid < 256) {
            const int tn = (t + 1 < TT) ? t + 1 : t;
            xv0 = ((const nf4*)(xb + tn * FF))[0];
            xv1 = ((const nf4*)(xb + tn * FF))[1];
            int n0 = s_total[0];
            float c = bhc0 + scan_chunks(s_list[0], n0, Wb0);
            UPDATE_PUBLISH(m1, 1, c, hrow + HH);
        } else {
            if (tid == 256) s_total[2] = 0;   // read P_C(t-1); safe now
            if (t > 0) {
                // readout for t-1 from layer-3 ballot masks (published P_C(t-1));
                // s_mask3 not rewritten until P_C(t), so reads here are safe.
                unsigned sm = ((const unsigned*)s_mask3)[seg];
                float acc = 0.f;
                while (sm) {
                    int r = __builtin_ctz(sm);
                    sm &= sm - 1;
                    acc += Wout[((seg << 5) + r) * OO + o8];
                }
                acc += __shfl_xor(acc, 8);
                acc += __shfl_xor(acc, 16);
                acc += __shfl_xor(acc, 32);
                if (lane < 8) {
                    ro = BETA * ro + (acc + boutc);
                    __builtin_nontemporal_store(ro, out_o + (t - 1) * OO + lane);
                    __builtin_nontemporal_store(ro, out_r + (t - 1) * OO + lane);
                }
            }
        }
        __syncthreads();      // B_A

        // ---- P_B: scan list1 -> layer-2 ----
        if (tid < 256) {
            int n1 = s_total[1];
            float c = bhc1 + scan_chunks(s_list[1], n1, Wb1);
            UPDATE_PUBLISH(m2, 2, c, hrow + 2 * HH);
        } else if (tid == 256) {
            s_total[0] = 0;   // read P_A(t); atomic'd next in P_C(t)
        }
        __syncthreads();      // B_B

        // ---- P_C: scan list2 -> layer-3 + mask publish;
        //           layer-0 for t+1 folded in (independent of this t's chain,
        //           its publish latency hides under scan2's load stalls) ----
        if (tid < 256) {
            int n2 = s_total[2];
            float c2 = bhc2 + scan_chunks(s_list[2], n2, Wb2);

            if (t + 1 < TT) {
                float c0 = b1c + xv0.x * w1c[0] + xv0.y * w1c[1] + xv0.z * w1c[2] + xv0.w * w1c[3]
                               + xv1.x * w1c[4] + xv1.y * w1c[5] + xv1.z * w1c[6] + xv1.w * w1c[7];
                UPDATE_PUBLISH(m0, 0, c0, hrow + LL * HH);   // row t+1, layer 0
            }

            float reset_ = (m3 > THRV) ? THRV : 0.f;
            m3 = BETA * m3 + c2 - reset_;
            int spk_ = (m3 > THRV) ? 1 : 0;
            __builtin_nontemporal_store(m3, hrow + 3 * HH + h);
            unsigned long long bm_ = __ballot(spk_);
            if (lane == 0) s_mask3[wave] = bm_;
        } else if (tid == 256) {
            s_total[1] = 0;   // read P_B(t); atomic'd next in P_A(t+1)
        }
        __syncthreads();      // B_C
    }

    // final readout for t = TT-1 (masks published before the last B_C)
    if (wave == 4) {
        unsigned sm = ((const unsigned*)s_mask3)[seg];
        float acc = 0.f;
        while (sm) {
            int r = __builtin_ctz(sm);
            sm &= sm - 1;
            acc += Wout[((seg << 5) + r) * OO + o8];
        }
        acc += __shfl_xor(acc, 8);
        acc += __shfl_xor(acc, 16);
        acc += __shfl_xor(acc, 32);
        if (lane < 8) {
            ro = BETA * ro + (acc + boutc);
            __builtin_nontemporal_store(ro, out_o + (TT - 1) * OO + lane);
            __builtin_nontemporal_store(ro, out_r + (TT - 1) * OO + lane);
        }
    }
}

extern "C" void kernel_launch(void* const* d_in, const int* in_sizes, int n_in,
                              void* d_out, int out_size, void* d_ws, size_t ws_size,
                              hipStream_t stream) {
    const float* x       = (const float*)d_in[0];
    const float* hidden  = (const float*)d_in[1];
    // d_in[2] = prev_obs (unused by the recurrence)
    const float* readout = (const float*)d_in[3];
    const float* W1      = (const float*)d_in[4];
    const float* b1      = (const float*)d_in[5];
    const float* Wh      = (const float*)d_in[6];
    const float* bh      = (const float*)d_in[7];
    const float* Wout    = (const float*)d_in[8];
    const float* bout    = (const float*)d_in[9];
    float* out = (float*)d_out;

    snn_kernel<<<dim3(BB), dim3(320), 0, stream>>>(
        x, hidden, readout, W1, b1, Wh, bh, Wout, bout, out);
}